// Round 11
// baseline (36.784 us; speedup 1.0000x reference)
//
#include <hip/hip_runtime.h>
#include <cmath>

#define NCLS 6
#define GRP 256
#define DIM 256
#define NBLK 768   // 6 classes x 128 blocks (2 anchors each) = exactly 3 blocks/CU

typedef __attribute__((ext_vector_type(8))) short short8;
typedef __attribute__((ext_vector_type(4))) float f32x4;

__device__ inline unsigned short f2bf(float f) {
    unsigned u = __float_as_uint(f);
    return (unsigned short)((u + 0x7FFFu + ((u >> 16) & 1u)) >> 16);
}

// ---------------- K0: bf16 hi/lo split into MFMA fragment layout + row norms ----
// (verbatim from R7/R10 — verified correct+fast)
// frag[(tileIdx*8 + kb)*64 + lane][e]: lane l holds row tile*16+(l&15),
// k = kb*32 + (l>>4)*8 + e.  Grid: 96 blocks x 256 threads.
__global__ __launch_bounds__(256) void prep_kernel(
    const float* __restrict__ feat,
    unsigned short* __restrict__ hifrag,
    unsigned short* __restrict__ lofrag,
    float* __restrict__ n2,
    unsigned int* __restrict__ counter)
{
    __shared__ float n2p[16][17];
    const int b = blockIdx.x;                 // b = cls*16 + tile
    const int t = threadIdx.x;
    if (b == 0 && t == 0)
        __hip_atomic_store(counter, 0u, __ATOMIC_RELAXED, __HIP_MEMORY_SCOPE_AGENT);

    const int rowbase = ((b >> 4) << 8) + ((b & 15) << 4);   // cls*256 + tile*16

    #pragma unroll
    for (int pi = 0; pi < 2; ++pi) {
        const int p    = t + (pi << 8);       // fragment position: p = kb*64 + lane
        const int kb   = p >> 6;
        const int lane = p & 63;
        const int row  = rowbase + (lane & 15);
        const int k0   = (kb << 5) + ((lane >> 4) << 3);

        const float* src = feat + (size_t)row * DIM + k0;
        float4 v0 = *reinterpret_cast<const float4*>(src);
        float4 v1 = *reinterpret_cast<const float4*>(src + 4);
        float fv[8] = {v0.x, v0.y, v0.z, v0.w, v1.x, v1.y, v1.z, v1.w};

        short8 h, lo;
        #pragma unroll
        for (int e = 0; e < 8; ++e) {
            unsigned short hb = f2bf(fv[e]);
            float hf = __uint_as_float((unsigned)hb << 16);
            h[e]  = (short)hb;
            lo[e] = (short)f2bf(fv[e] - hf);
        }
        const size_t fidx = ((size_t)(b * 8 + kb) * 64 + lane) * 8;
        *reinterpret_cast<short8*>(hifrag + fidx) = h;    // coalesced 16B/lane
        *reinterpret_cast<short8*>(lofrag + fidx) = lo;
    }

    // exact f32 row norms
    {
        const int r16 = t >> 4, chunk = t & 15;
        const float* src = feat + (size_t)(rowbase + r16) * DIM + (chunk << 4);
        float s = 0.f;
        #pragma unroll
        for (int q = 0; q < 4; ++q) {
            float4 v = *reinterpret_cast<const float4*>(src + (q << 2));
            s += v.x * v.x + v.y * v.y + v.z * v.z + v.w * v.w;
        }
        n2p[r16][chunk] = s;
    }
    __syncthreads();
    if (t < 16) {
        float s = 0.f;
        #pragma unroll
        for (int q = 0; q < 16; ++q) s += n2p[t][q];
        n2[rowbase + t] = s;
    }
}

// ---------------- K1: MFMA gram -> lg, labels + denom + reduction ----------------
// 768 blocks x 256 threads (4 waves); block owns 2 anchors (cls = b>>7, pair = b&127,
// anchors = cls*256 + pair*2 + {0,1}). Exactly 3 blocks/CU -> balanced, and 3
// independent blocks per CU overlap each other's barriers and memory waits.
// Gram: wave w does j-tiles {w, w+4, w+8, w+12}; C/D map col=lane&15, row=(lane>>4)*4+r.
__global__ __launch_bounds__(256, 4) void rnc_main_kernel(
    const unsigned short* __restrict__ hifrag,
    const unsigned short* __restrict__ lofrag,
    const float* __restrict__ n2,
    const float* __restrict__ green,
    const float* __restrict__ red,
    const float* __restrict__ trans,
    const int*   __restrict__ sym,
    float* __restrict__ partial,       // [768]
    unsigned int* __restrict__ counter,
    float* __restrict__ out)
{
    __shared__ float lgs[2][GRP];                    // lg = -dist/2
    __shared__ __align__(16) float2 LEs[2][GRP];     // (L, ev)
    __shared__ __align__(16) float pdn[2][GRP][2];   // per-k-half denom partials
    __shared__ float rbuf[4];
    __shared__ int iswin;

    const int b    = blockIdx.x;
    const int cls  = b >> 7;           // class
    const int pair = b & 127;          // anchor pair within class
    const int it   = pair >> 3;        // 16-row i-tile
    const int ra   = (pair & 7) << 1;  // first anchor row within tile (even)
    const int qa   = ra >> 2;          // lane quarter holding our rows
    const int rr   = ra & 3;           // reg index of first anchor (0 or 2)
    const int base = cls << 8;
    const int ia0  = pair << 1;        // in-class anchor index of p=0
    const int a0g  = base + ia0;
    const int t    = threadIdx.x;
    const int w    = t >> 6;
    const int lane = t & 63;

    // ---- gram phase: wave w handles j-tiles {w, w+4, w+8, w+12} ----
    {
        const int tA = (cls << 4) + it;
        const float n2a0 = n2[a0g];
        const float n2a1 = n2[a0g + 1];

        #pragma unroll
        for (int jj = 0; jj < 4; ++jj) {
            const int jt = w + (jj << 2);          // wave-uniform
            const int tB = (cls << 4) + jt;
            f32x4 acc = {0.f, 0.f, 0.f, 0.f};
            #pragma unroll
            for (int kb = 0; kb < 8; ++kb) {
                const size_t ia = ((size_t)(tA * 8 + kb) * 64 + lane) * 8;
                const size_t ib = ((size_t)(tB * 8 + kb) * 64 + lane) * 8;
                short8 ah = *reinterpret_cast<const short8*>(hifrag + ia);
                short8 al = *reinterpret_cast<const short8*>(lofrag + ia);
                short8 bh = *reinterpret_cast<const short8*>(hifrag + ib);
                short8 bl = *reinterpret_cast<const short8*>(lofrag + ib);
                acc = __builtin_amdgcn_mfma_f32_16x16x32_bf16(ah, bh, acc, 0, 0, 0);
                acc = __builtin_amdgcn_mfma_f32_16x16x32_bf16(ah, bl, acc, 0, 0, 0);
                acc = __builtin_amdgcn_mfma_f32_16x16x32_bf16(al, bh, acc, 0, 0, 0);
            }
            if ((lane >> 4) == qa) {
                const int colj = (jt << 4) + (lane & 15);
                const float njv = n2[base + colj];
                // rr is block-uniform (0 or 2): static-select both anchor rows
                float g0 = (rr == 0) ? acc[0] : acc[2];
                float g1 = (rr == 0) ? acc[1] : acc[3];
                float d20 = n2a0 + njv - 2.f * g0;
                float d21 = n2a1 + njv - 2.f * g1;
                lgs[0][colj] = -0.5f * sqrtf(fmaxf(d20, 0.f) + 1e-12f);
                lgs[1][colj] = -0.5f * sqrtf(fmaxf(d21, 0.f) + 1e-12f);
            }
        }
    }
    __syncthreads();

    // ---- phase 2: labels + ev; thread t owns column col = t ----
    {
        const int col = t;
        const int kg  = base + col;
        float kgx = green[3*kg], kgy = green[3*kg+1], kgz = green[3*kg+2];
        float ktx = trans[3*kg], kty = trans[3*kg+1], ktz = trans[3*kg+2];
        float krx = 0.f, kry = 0.f, krz = 0.f;
        int ksym = 0;
        if (cls >= 2) { krx = red[3*kg]; kry = red[3*kg+1]; krz = red[3*kg+2]; }
        if (cls == 5) ksym = sym[4*kg];

        #pragma unroll
        for (int p = 0; p < 2; ++p) {
            const int ag = a0g + p;            // block-uniform
            float lg = lgs[p][col];

            float l1g = fabsf(green[3*ag] - kgx) + fabsf(green[3*ag+1] - kgy)
                      + fabsf(green[3*ag+2] - kgz);
            float l1t = fabsf(trans[3*ag] - ktx) + fabsf(trans[3*ag+1] - kty)
                      + fabsf(trans[3*ag+2] - ktz);
            float L;
            if (cls < 2) {
                L = 0.8f * l1g + 0.2f * l1t;
            } else {
                float l1r = fabsf(red[3*ag] - krx) + fabsf(red[3*ag+1] - kry)
                          + fabsf(red[3*ag+2] - krz);
                float rot;
                if (cls < 5) {
                    rot = 0.5f * (l1g + l1r);
                } else {
                    float both = ((sym[4*ag] == 0) && (ksym == 0)) ? 1.f : 0.f;
                    rot = (l1g + both * l1r) / (1.f + both);
                }
                L = 0.8f * rot + 0.2f * l1t;
            }
            LEs[p][col] = make_float2(L, __expf(lg));
        }
    }
    __syncthreads();

    // ---- phase 3: denom scan. wave w: anchor p = w&1, k-half hh = w>>1 ----
    const int l  = lane;
    const int p  = w & 1;
    const int hh = w >> 1;

    float L0 = LEs[p][l].x;
    float L1 = LEs[p][l + 64].x;
    float L2 = LEs[p][l + 128].x;
    float L3 = LEs[p][l + 192].x;

    const float4* q4 = reinterpret_cast<const float4*>(LEs[p]);
    float dn0 = 0.f, dn1 = 0.f, dn2 = 0.f, dn3 = 0.f;
    #pragma unroll 8
    for (int q = hh * 64; q < hh * 64 + 64; ++q) {
        float4 u = q4[q];                 // uniform broadcast: (L,ev) x2
        dn0 += (u.x >= L0) ? u.y : 0.f;  dn0 += (u.z >= L0) ? u.w : 0.f;
        dn1 += (u.x >= L1) ? u.y : 0.f;  dn1 += (u.z >= L1) ? u.w : 0.f;
        dn2 += (u.x >= L2) ? u.y : 0.f;  dn2 += (u.z >= L2) ? u.w : 0.f;
        dn3 += (u.x >= L3) ? u.y : 0.f;  dn3 += (u.z >= L3) ? u.w : 0.f;
    }
    pdn[p][l][hh]       = dn0;
    pdn[p][l + 64][hh]  = dn1;
    pdn[p][l + 128][hh] = dn2;
    pdn[p][l + 192][hh] = dn3;
    __syncthreads();

    // ---- per-block log-prob sum over the 2 anchors; j = t ----
    float acc2 = 0.f;
    #pragma unroll
    for (int pp = 0; pp < 2; ++pp) {
        float dn = pdn[pp][t][0] + pdn[pp][t][1];
        float v  = lgs[pp][t] - __logf(dn);
        acc2 += (t != ia0 + pp) ? v : 0.f;
    }
    #pragma unroll
    for (int off = 32; off > 0; off >>= 1)
        acc2 += __shfl_xor(acc2, off);
    if (l == 0) rbuf[w] = acc2;
    __syncthreads();
    if (t == 0) {
        float s = (rbuf[0] + rbuf[1]) + (rbuf[2] + rbuf[3]);
        __hip_atomic_store(&partial[b], s, __ATOMIC_RELAXED, __HIP_MEMORY_SCOPE_AGENT);
        unsigned int old = __hip_atomic_fetch_add(counter, 1u, __ATOMIC_ACQ_REL,
                                                  __HIP_MEMORY_SCOPE_AGENT);
        iswin = (old == NBLK - 1) ? 1 : 0;
    }
    __syncthreads();

    // ---- last block: final deterministic reduction over 768 partials ----
    if (iswin) {
        float a2 = __hip_atomic_load(&partial[t], __ATOMIC_RELAXED, __HIP_MEMORY_SCOPE_AGENT)
                 + __hip_atomic_load(&partial[t + 256], __ATOMIC_RELAXED, __HIP_MEMORY_SCOPE_AGENT)
                 + __hip_atomic_load(&partial[t + 512], __ATOMIC_RELAXED, __HIP_MEMORY_SCOPE_AGENT);
        #pragma unroll
        for (int off = 32; off > 0; off >>= 1)
            a2 += __shfl_xor(a2, off);
        __syncthreads();
        if (l == 0) rbuf[w] = a2;
        __syncthreads();
        if (t == 0) {
            float s = (rbuf[0] + rbuf[1]) + (rbuf[2] + rbuf[3]);
            out[0] = -s / (256.f * 255.f * 6.f);
        }
    }
}

extern "C" void kernel_launch(void* const* d_in, const int* in_sizes, int n_in,
                              void* d_out, int out_size, void* d_ws, size_t ws_size,
                              hipStream_t stream)
{
    const float* feat  = (const float*)d_in[0];
    // d_in[1] = labels: unused (classes are contiguous GROUP-sized slices)
    const float* green = (const float*)d_in[2];
    const float* red   = (const float*)d_in[3];
    const float* trans = (const float*)d_in[4];
    const int*   sym   = (const int*)d_in[5];

    float* wsf = (float*)d_ws;
    float*          partial = wsf;                          // 768 f32
    unsigned int*   counter = (unsigned int*)(wsf + 1024);  // 1 u32
    float*          n2      = wsf + 2048;                   // 1536 f32
    unsigned short* hifrag  = (unsigned short*)(wsf + 4096);
    unsigned short* lofrag  = hifrag + (size_t)NCLS * GRP * DIM;
    float* out = (float*)d_out;

    prep_kernel    <<<NCLS * 16, 256, 0, stream>>>(feat, hifrag, lofrag, n2, counter);
    rnc_main_kernel<<<NBLK, 256, 0, stream>>>(hifrag, lofrag, n2,
                                              green, red, trans, sym,
                                              partial, counter, out);
}

// Round 12
// 34.998 us; speedup vs baseline: 1.0510x; 1.0510x over previous
//
#include <hip/hip_runtime.h>
#include <cmath>

#define NCLS 6
#define GRP 256
#define DIM 256
#define NBLK 384   // 6 classes x 64 blocks (4 anchors each)

// ws layout (floats): [0..384) partial, [512] counter (uint, memset to 0 per call)

__device__ __forceinline__ float dot4(float4 a, float4 v, float acc) {
    return fmaf(a.x, v.x, fmaf(a.y, v.y, fmaf(a.z, v.z, fmaf(a.w, v.w, acc))));
}

// Single fused kernel: rowwise dist (in-wave butterfly) + labels + denom + reduction.
// 384 blocks x 512 threads (8 waves), 4 anchors/block.
// Phase 1: wave w owns k in [32w, 32w+32). Lane l: d-slice [16*(l&15), +16),
//          k-subgroup kq = l>>4 (4 k per iteration). dist^2 = n2a + n2v - 2*dot.
__global__ __launch_bounds__(512, 4) void rnc_fused_kernel(
    const float* __restrict__ feat,
    const float* __restrict__ green,
    const float* __restrict__ red,
    const float* __restrict__ trans,
    const int*   __restrict__ sym,
    float* __restrict__ partial,       // [384]
    unsigned int* __restrict__ counter,
    float* __restrict__ out)
{
    __shared__ __align__(16) float4 dist4[GRP];      // dist^2 of 4 anchors vs k
    __shared__ __align__(16) float2 LEs[4][GRP];     // (L, ev)
    __shared__ float lgs[4][GRP];                    // lg = -dist/2
    __shared__ __align__(16) float pdn[4][GRP][2];   // per-k-half denom partials
    __shared__ float rbuf[8];
    __shared__ int iswin;

    const int b    = blockIdx.x;
    const int c    = b >> 6;           // class
    const int a0   = (b & 63) << 2;    // first in-class anchor
    const int base = c << 8;
    const int a0g  = base + a0;
    const int t    = threadIdx.x;
    const int w    = t >> 6;
    const int lane = t & 63;
    const int p16  = lane & 15;        // d-slice selector
    const int kq   = lane >> 4;        // k-subgroup 0..3

    // ================= phase 1: rowwise dist^2, in-wave butterfly =================
    {
        // preload anchor d-slices (coalesced within 16-lane groups; 4x redundant)
        const float* ap = feat + (size_t)a0g * DIM + (p16 << 4);
        float4 av[4][4];
        #pragma unroll
        for (int p = 0; p < 4; ++p)
            #pragma unroll
            for (int q = 0; q < 4; ++q)
                av[p][q] = *reinterpret_cast<const float4*>(ap + (size_t)p * DIM + (q << 2));

        // anchor norms (butterfly-allreduce over the 16-lane group)
        float n2a[4];
        #pragma unroll
        for (int p = 0; p < 4; ++p) {
            float s = dot4(av[p][0], av[p][0],
                      dot4(av[p][1], av[p][1],
                      dot4(av[p][2], av[p][2],
                      dot4(av[p][3], av[p][3], 0.f))));
            #pragma unroll
            for (int off = 1; off < 16; off <<= 1)
                s += __shfl_xor(s, off);
            n2a[p] = s;
        }

        #pragma unroll 2
        for (int i = 0; i < 8; ++i) {
            const int k = (w << 5) + (i << 2) + kq;
            const float4* kr = reinterpret_cast<const float4*>(
                feat + (size_t)(base + k) * DIM + (p16 << 4));
            float4 kv0 = kr[0], kv1 = kr[1], kv2 = kr[2], kv3 = kr[3];

            float d0 = dot4(av[0][0], kv0, dot4(av[0][1], kv1,
                       dot4(av[0][2], kv2, dot4(av[0][3], kv3, 0.f))));
            float d1 = dot4(av[1][0], kv0, dot4(av[1][1], kv1,
                       dot4(av[1][2], kv2, dot4(av[1][3], kv3, 0.f))));
            float d2 = dot4(av[2][0], kv0, dot4(av[2][1], kv1,
                       dot4(av[2][2], kv2, dot4(av[2][3], kv3, 0.f))));
            float d3 = dot4(av[3][0], kv0, dot4(av[3][1], kv1,
                       dot4(av[3][2], kv2, dot4(av[3][3], kv3, 0.f))));
            float nv = dot4(kv0, kv0, dot4(kv1, kv1,
                       dot4(kv2, kv2, dot4(kv3, kv3, 0.f))));

            #pragma unroll
            for (int off = 1; off < 16; off <<= 1) {
                d0 += __shfl_xor(d0, off);
                d1 += __shfl_xor(d1, off);
                d2 += __shfl_xor(d2, off);
                d3 += __shfl_xor(d3, off);
                nv += __shfl_xor(nv, off);
            }
            if (p16 == 0)
                dist4[k] = make_float4(n2a[0] + nv - 2.f * d0,
                                       n2a[1] + nv - 2.f * d1,
                                       n2a[2] + nv - 2.f * d2,
                                       n2a[3] + nv - 2.f * d3);
        }
    }
    __syncthreads();

    // ================= phase 2: labels + ev (R10 verbatim) =================
    const int col = t & 255;
    const int dh  = t >> 8;            // wave-uniform
    {
        const int kg = base + col;
        float kgx = green[3*kg], kgy = green[3*kg+1], kgz = green[3*kg+2];
        float ktx = trans[3*kg], kty = trans[3*kg+1], ktz = trans[3*kg+2];
        float krx = 0.f, kry = 0.f, krz = 0.f;
        int ksym = 0;
        if (c >= 2) { krx = red[3*kg]; kry = red[3*kg+1]; krz = red[3*kg+2]; }
        if (c == 5) ksym = sym[4*kg];

        const float* d4f = reinterpret_cast<const float*>(dist4);
        #pragma unroll
        for (int e = 0; e < 2; ++e) {
            const int p  = dh + 2 * e;     // wave-uniform
            const int ag = a0g + p;
            float s  = d4f[(col << 2) + p];
            float lg = -0.5f * sqrtf(fmaxf(s, 0.f) + 1e-12f);

            float l1g = fabsf(green[3*ag] - kgx) + fabsf(green[3*ag+1] - kgy)
                      + fabsf(green[3*ag+2] - kgz);
            float l1t = fabsf(trans[3*ag] - ktx) + fabsf(trans[3*ag+1] - kty)
                      + fabsf(trans[3*ag+2] - ktz);
            float L;
            if (c < 2) {
                L = 0.8f * l1g + 0.2f * l1t;
            } else {
                float l1r = fabsf(red[3*ag] - krx) + fabsf(red[3*ag+1] - kry)
                          + fabsf(red[3*ag+2] - krz);
                float rot;
                if (c < 5) {
                    rot = 0.5f * (l1g + l1r);
                } else {
                    float both = ((sym[4*ag] == 0) && (ksym == 0)) ? 1.f : 0.f;
                    rot = (l1g + both * l1r) / (1.f + both);
                }
                L = 0.8f * rot + 0.2f * l1t;
            }
            LEs[p][col] = make_float2(L, __expf(lg));
            lgs[p][col] = lg;
        }
    }
    __syncthreads();

    // ================= phase 3: denom scan (R10 verbatim) =================
    const int l  = lane;
    const int p  = w & 3;
    const int hh = w >> 2;

    float L0 = LEs[p][l].x;
    float L1 = LEs[p][l + 64].x;
    float L2 = LEs[p][l + 128].x;
    float L3 = LEs[p][l + 192].x;

    const float4* q4 = reinterpret_cast<const float4*>(LEs[p]);
    float dn0 = 0.f, dn1 = 0.f, dn2 = 0.f, dn3 = 0.f;
    #pragma unroll 8
    for (int q = hh * 64; q < hh * 64 + 64; ++q) {
        float4 u = q4[q];                 // uniform broadcast: (L,ev) x2
        dn0 += (u.x >= L0) ? u.y : 0.f;  dn0 += (u.z >= L0) ? u.w : 0.f;
        dn1 += (u.x >= L1) ? u.y : 0.f;  dn1 += (u.z >= L1) ? u.w : 0.f;
        dn2 += (u.x >= L2) ? u.y : 0.f;  dn2 += (u.z >= L2) ? u.w : 0.f;
        dn3 += (u.x >= L3) ? u.y : 0.f;  dn3 += (u.z >= L3) ? u.w : 0.f;
    }
    pdn[p][l][hh]       = dn0;
    pdn[p][l + 64][hh]  = dn1;
    pdn[p][l + 128][hh] = dn2;
    pdn[p][l + 192][hh] = dn3;
    __syncthreads();

    // ================= per-block log-prob sum over 4 anchors =================
    float acc = 0.f;
    #pragma unroll
    for (int e = 0; e < 2; ++e) {
        int idx = t + e * 512;            // 1024 (p,j) pairs over 512 threads
        int pp  = idx >> 8;
        int j   = idx & 255;
        float dn = pdn[pp][j][0] + pdn[pp][j][1];
        float v  = lgs[pp][j] - __logf(dn);
        acc += (j != a0 + pp) ? v : 0.f;
    }
    #pragma unroll
    for (int off = 32; off > 0; off >>= 1)
        acc += __shfl_xor(acc, off);
    if (l == 0) rbuf[w] = acc;
    __syncthreads();
    if (t == 0) {
        float s = 0.f;
        #pragma unroll
        for (int k = 0; k < 8; ++k) s += rbuf[k];
        __hip_atomic_store(&partial[b], s, __ATOMIC_RELAXED, __HIP_MEMORY_SCOPE_AGENT);
        unsigned int old = __hip_atomic_fetch_add(counter, 1u, __ATOMIC_ACQ_REL,
                                                  __HIP_MEMORY_SCOPE_AGENT);
        iswin = (old == NBLK - 1) ? 1 : 0;
    }
    __syncthreads();

    // ================= last block: final deterministic reduction =================
    if (iswin) {
        float a2 = 0.f;
        if (t < NBLK)
            a2 = __hip_atomic_load(&partial[t], __ATOMIC_RELAXED, __HIP_MEMORY_SCOPE_AGENT);
        #pragma unroll
        for (int off = 32; off > 0; off >>= 1)
            a2 += __shfl_xor(a2, off);
        __syncthreads();
        if (l == 0) rbuf[w] = a2;
        __syncthreads();
        if (t == 0) {
            float s = 0.f;
            #pragma unroll
            for (int k = 0; k < 8; ++k) s += rbuf[k];
            out[0] = -s / (256.f * 255.f * 6.f);
        }
    }
}

extern "C" void kernel_launch(void* const* d_in, const int* in_sizes, int n_in,
                              void* d_out, int out_size, void* d_ws, size_t ws_size,
                              hipStream_t stream)
{
    const float* feat  = (const float*)d_in[0];
    // d_in[1] = labels: unused (classes are contiguous GROUP-sized slices)
    const float* green = (const float*)d_in[2];
    const float* red   = (const float*)d_in[3];
    const float* trans = (const float*)d_in[4];
    const int*   sym   = (const int*)d_in[5];

    float*        wsf     = (float*)d_ws;
    float*        partial = wsf;                         // 384 floats
    unsigned int* counter = (unsigned int*)(wsf + 512);  // 1 uint
    float*        out     = (float*)d_out;

    hipMemsetAsync(counter, 0, sizeof(unsigned int), stream);
    rnc_fused_kernel<<<NBLK, 512, 0, stream>>>(feat, green, red, trans, sym,
                                               partial, counter, out);
}

// Round 13
// 32.040 us; speedup vs baseline: 1.1481x; 1.0923x over previous
//
#include <hip/hip_runtime.h>
#include <cmath>

#define NCLS 6
#define GRP 256
#define DIM 256
#define NBLK (NCLS * 64)   // 384 main blocks

typedef __attribute__((ext_vector_type(8))) short short8;
typedef __attribute__((ext_vector_type(4))) float f32x4;

__device__ inline unsigned short f2bf(float f) {
    unsigned u = __float_as_uint(f);
    return (unsigned short)((u + 0x7FFFu + ((u >> 16) & 1u)) >> 16);
}

// ---------------- K0: bf16 hi/lo split into MFMA fragment layout + row norms ----
// (verbatim from R7/R10 — verified correct)
__global__ __launch_bounds__(256) void prep_kernel(
    const float* __restrict__ feat,
    unsigned short* __restrict__ hifrag,
    unsigned short* __restrict__ lofrag,
    float* __restrict__ n2,
    unsigned int* __restrict__ counter)
{
    __shared__ float n2p[16][17];
    const int b = blockIdx.x;                 // b = cls*16 + tile
    const int t = threadIdx.x;
    if (b == 0 && t == 0)
        __hip_atomic_store(counter, 0u, __ATOMIC_RELAXED, __HIP_MEMORY_SCOPE_AGENT);

    const int rowbase = ((b >> 4) << 8) + ((b & 15) << 4);   // cls*256 + tile*16

    #pragma unroll
    for (int pi = 0; pi < 2; ++pi) {
        const int p    = t + (pi << 8);       // fragment position: p = kb*64 + lane
        const int kb   = p >> 6;
        const int lane = p & 63;
        const int row  = rowbase + (lane & 15);
        const int k0   = (kb << 5) + ((lane >> 4) << 3);

        const float* src = feat + (size_t)row * DIM + k0;
        float4 v0 = *reinterpret_cast<const float4*>(src);
        float4 v1 = *reinterpret_cast<const float4*>(src + 4);
        float fv[8] = {v0.x, v0.y, v0.z, v0.w, v1.x, v1.y, v1.z, v1.w};

        short8 h, lo;
        #pragma unroll
        for (int e = 0; e < 8; ++e) {
            unsigned short hb = f2bf(fv[e]);
            float hf = __uint_as_float((unsigned)hb << 16);
            h[e]  = (short)hb;
            lo[e] = (short)f2bf(fv[e] - hf);
        }
        const size_t fidx = ((size_t)(b * 8 + kb) * 64 + lane) * 8;
        *reinterpret_cast<short8*>(hifrag + fidx) = h;    // coalesced 16B/lane
        *reinterpret_cast<short8*>(lofrag + fidx) = lo;
    }

    // exact f32 row norms
    {
        const int r16 = t >> 4, chunk = t & 15;
        const float* src = feat + (size_t)(rowbase + r16) * DIM + (chunk << 4);
        float s = 0.f;
        #pragma unroll
        for (int q = 0; q < 4; ++q) {
            float4 v = *reinterpret_cast<const float4*>(src + (q << 2));
            s += v.x * v.x + v.y * v.y + v.z * v.z + v.w * v.w;
        }
        n2p[r16][chunk] = s;
    }
    __syncthreads();
    if (t < 16) {
        float s = 0.f;
        #pragma unroll
        for (int q = 0; q < 16; ++q) s += n2p[t][q];
        n2[rowbase + t] = s;
    }
}

// ---------------- K1: MFMA gram -> lg, then labels + denom + reduction ----------------
// 384 blocks x 512 threads (8 waves), (512,4) -> 2 blocks/CU, 16 waves/CU.
// Gram: kb-outer / dual-accumulator (A-tile loaded once per kb).
// C/D map (verified): col = lane&15, row = (lane>>4)*4 + reg.
__global__ __launch_bounds__(512, 4) void rnc_main_kernel(
    const unsigned short* __restrict__ hifrag,
    const unsigned short* __restrict__ lofrag,
    const float* __restrict__ n2,
    const float* __restrict__ green,
    const float* __restrict__ red,
    const float* __restrict__ trans,
    const int*   __restrict__ sym,
    float* __restrict__ partial,       // [384]
    unsigned int* __restrict__ counter,
    float* __restrict__ out)
{
    __shared__ float lgs[4][GRP];                    // lg = -dist/2
    __shared__ __align__(16) float2 LEs[4][GRP];     // (L, ev)
    __shared__ __align__(16) float pdn[4][GRP][2];   // per-k-half denom partials
    __shared__ float rbuf[8];
    __shared__ int iswin;

    const int b    = blockIdx.x;
    const int cls  = b >> 6;
    const int sub  = b & 63;
    const int it   = sub >> 2;         // i-tile (16 rows)
    const int qq   = sub & 3;          // 4-anchor quarter within the tile
    const int base = cls << 8;
    const int a0   = sub << 2;         // first in-class anchor = it*16 + qq*4
    const int a0g  = base + a0;
    const int t    = threadIdx.x;
    const int w    = t >> 6;
    const int lane = t & 63;

    // ---- gram phase: wave w handles j-tiles {w, w+8}; A loaded once per kb ----
    {
        const int tA  = (cls << 4) + it;
        const int tB0 = (cls << 4) + w;
        const int tB1 = tB0 + 8;
        f32x4 acc0 = {0.f, 0.f, 0.f, 0.f};
        f32x4 acc1 = {0.f, 0.f, 0.f, 0.f};
        #pragma unroll
        for (int kb = 0; kb < 8; ++kb) {
            const size_t ia  = ((size_t)(tA  * 8 + kb) * 64 + lane) * 8;
            const size_t ib0 = ((size_t)(tB0 * 8 + kb) * 64 + lane) * 8;
            const size_t ib1 = ((size_t)(tB1 * 8 + kb) * 64 + lane) * 8;
            short8 ah  = *reinterpret_cast<const short8*>(hifrag + ia);
            short8 al  = *reinterpret_cast<const short8*>(lofrag + ia);
            short8 b0h = *reinterpret_cast<const short8*>(hifrag + ib0);
            short8 b0l = *reinterpret_cast<const short8*>(lofrag + ib0);
            short8 b1h = *reinterpret_cast<const short8*>(hifrag + ib1);
            short8 b1l = *reinterpret_cast<const short8*>(lofrag + ib1);
            acc0 = __builtin_amdgcn_mfma_f32_16x16x32_bf16(ah, b0h, acc0, 0, 0, 0);
            acc0 = __builtin_amdgcn_mfma_f32_16x16x32_bf16(ah, b0l, acc0, 0, 0, 0);
            acc0 = __builtin_amdgcn_mfma_f32_16x16x32_bf16(al, b0h, acc0, 0, 0, 0);
            acc1 = __builtin_amdgcn_mfma_f32_16x16x32_bf16(ah, b1h, acc1, 0, 0, 0);
            acc1 = __builtin_amdgcn_mfma_f32_16x16x32_bf16(ah, b1l, acc1, 0, 0, 0);
            acc1 = __builtin_amdgcn_mfma_f32_16x16x32_bf16(al, b1h, acc1, 0, 0, 0);
        }
        if ((lane >> 4) == qq) {
            float n2a[4];
            #pragma unroll
            for (int r = 0; r < 4; ++r) n2a[r] = n2[a0g + r];
            #pragma unroll
            for (int jj = 0; jj < 2; ++jj) {
                const int jt   = w + (jj << 3);
                const int colj = (jt << 4) + (lane & 15);
                const float nj = n2[base + colj];
                const f32x4 acc = jj ? acc1 : acc0;
                #pragma unroll
                for (int r = 0; r < 4; ++r) {
                    float d2 = n2a[r] + nj - 2.f * acc[r];
                    lgs[r][colj] = -0.5f * sqrtf(fmaxf(d2, 0.f) + 1e-12f);
                }
            }
        }
    }
    __syncthreads();

    // ---- phase 2: labels + ev ----
    const int col = t & 255;
    const int dh  = t >> 8;            // wave-uniform
    {
        const int kg = base + col;
        float kgx = green[3*kg], kgy = green[3*kg+1], kgz = green[3*kg+2];
        float ktx = trans[3*kg], kty = trans[3*kg+1], ktz = trans[3*kg+2];
        float krx = 0.f, kry = 0.f, krz = 0.f;
        int ksym = 0;
        if (cls >= 2) { krx = red[3*kg]; kry = red[3*kg+1]; krz = red[3*kg+2]; }
        if (cls == 5) ksym = sym[4*kg];

        #pragma unroll
        for (int e = 0; e < 2; ++e) {
            const int p  = dh + 2 * e;     // wave-uniform
            const int ag = a0g + p;
            float lg = lgs[p][col];

            float l1g = fabsf(green[3*ag] - kgx) + fabsf(green[3*ag+1] - kgy)
                      + fabsf(green[3*ag+2] - kgz);
            float l1t = fabsf(trans[3*ag] - ktx) + fabsf(trans[3*ag+1] - kty)
                      + fabsf(trans[3*ag+2] - ktz);
            float L;
            if (cls < 2) {
                L = 0.8f * l1g + 0.2f * l1t;
            } else {
                float l1r = fabsf(red[3*ag] - krx) + fabsf(red[3*ag+1] - kry)
                          + fabsf(red[3*ag+2] - krz);
                float rot;
                if (cls < 5) {
                    rot = 0.5f * (l1g + l1r);
                } else {
                    float both = ((sym[4*ag] == 0) && (ksym == 0)) ? 1.f : 0.f;
                    rot = (l1g + both * l1r) / (1.f + both);
                }
                L = 0.8f * rot + 0.2f * l1t;
            }
            LEs[p][col] = make_float2(L, __expf(lg));
        }
    }
    __syncthreads();

    // ---- phase 3: denom scan: wave w -> anchor p=w&3, k-half hh=w>>2 ----
    const int l  = lane;
    const int p  = w & 3;
    const int hh = w >> 2;

    float L0 = LEs[p][l].x;
    float L1 = LEs[p][l + 64].x;
    float L2 = LEs[p][l + 128].x;
    float L3 = LEs[p][l + 192].x;

    const float4* q4 = reinterpret_cast<const float4*>(LEs[p]);
    float dn0 = 0.f, dn1 = 0.f, dn2 = 0.f, dn3 = 0.f;
    #pragma unroll 8
    for (int q = hh * 64; q < hh * 64 + 64; ++q) {
        float4 u = q4[q];                 // uniform broadcast: (L,ev) x2
        dn0 += (u.x >= L0) ? u.y : 0.f;  dn0 += (u.z >= L0) ? u.w : 0.f;
        dn1 += (u.x >= L1) ? u.y : 0.f;  dn1 += (u.z >= L1) ? u.w : 0.f;
        dn2 += (u.x >= L2) ? u.y : 0.f;  dn2 += (u.z >= L2) ? u.w : 0.f;
        dn3 += (u.x >= L3) ? u.y : 0.f;  dn3 += (u.z >= L3) ? u.w : 0.f;
    }
    pdn[p][l][hh]       = dn0;
    pdn[p][l + 64][hh]  = dn1;
    pdn[p][l + 128][hh] = dn2;
    pdn[p][l + 192][hh] = dn3;
    __syncthreads();

    // ---- per-block log-prob sum over 4 anchors ----
    float acc = 0.f;
    #pragma unroll
    for (int e = 0; e < 2; ++e) {
        int idx = t + e * 512;            // 1024 (p,j) pairs over 512 threads
        int pp  = idx >> 8;
        int j   = idx & 255;
        float dn = pdn[pp][j][0] + pdn[pp][j][1];
        float v  = lgs[pp][j] - __logf(dn);
        acc += (j != a0 + pp) ? v : 0.f;
    }
    #pragma unroll
    for (int off = 32; off > 0; off >>= 1)
        acc += __shfl_xor(acc, off);
    if (l == 0) rbuf[w] = acc;
    __syncthreads();
    if (t == 0) {
        float s = 0.f;
        #pragma unroll
        for (int k = 0; k < 8; ++k) s += rbuf[k];
        __hip_atomic_store(&partial[b], s, __ATOMIC_RELAXED, __HIP_MEMORY_SCOPE_AGENT);
        unsigned int old = __hip_atomic_fetch_add(counter, 1u, __ATOMIC_ACQ_REL,
                                                  __HIP_MEMORY_SCOPE_AGENT);
        iswin = (old == NBLK - 1) ? 1 : 0;
    }
    __syncthreads();

    // ---- last block: final deterministic reduction ----
    if (iswin) {
        float a2 = 0.f;
        if (t < NBLK)
            a2 = __hip_atomic_load(&partial[t], __ATOMIC_RELAXED, __HIP_MEMORY_SCOPE_AGENT);
        #pragma unroll
        for (int off = 32; off > 0; off >>= 1)
            a2 += __shfl_xor(a2, off);
        __syncthreads();
        if (l == 0) rbuf[w] = a2;
        __syncthreads();
        if (t == 0) {
            float s = 0.f;
            #pragma unroll
            for (int k = 0; k < 8; ++k) s += rbuf[k];
            out[0] = -s / (256.f * 255.f * 6.f);
        }
    }
}

extern "C" void kernel_launch(void* const* d_in, const int* in_sizes, int n_in,
                              void* d_out, int out_size, void* d_ws, size_t ws_size,
                              hipStream_t stream)
{
    const float* feat  = (const float*)d_in[0];
    // d_in[1] = labels: unused (classes are contiguous GROUP-sized slices)
    const float* green = (const float*)d_in[2];
    const float* red   = (const float*)d_in[3];
    const float* trans = (const float*)d_in[4];
    const int*   sym   = (const int*)d_in[5];

    float* wsf = (float*)d_ws;
    float*          partial = wsf;                          // 384 f32
    unsigned int*   counter = (unsigned int*)(wsf + 512);   // 1 u32
    float*          n2      = wsf + 1024;                   // 1536 f32
    unsigned short* hifrag  = (unsigned short*)(wsf + 4096);
    unsigned short* lofrag  = hifrag + (size_t)NCLS * GRP * DIM;
    float* out = (float*)d_out;

    prep_kernel    <<<NCLS * 16, 256, 0, stream>>>(feat, hifrag, lofrag, n2, counter);
    rnc_main_kernel<<<NBLK, 512, 0, stream>>>(hifrag, lofrag, n2,
                                              green, red, trans, sym,
                                              partial, counter, out);
}